// Round 9
// baseline (451.261 us; speedup 1.0000x reference)
//
#include <hip/hip_runtime.h>

typedef __attribute__((ext_vector_type(8))) short short8;
typedef __attribute__((ext_vector_type(4))) float f32x4;
typedef __attribute__((ext_vector_type(16))) float f32x16;
typedef __attribute__((ext_vector_type(4))) unsigned short us4;
typedef __attribute__((ext_vector_type(4))) int i32x4;

__device__ __forceinline__ unsigned short f2bf(float f) {
  unsigned u = __builtin_bit_cast(unsigned, f);
  u += 0x7FFFu + ((u >> 16) & 1u);
  return (unsigned short)(u >> 16);
}

// RNE bf16 pair pack
__device__ __forceinline__ int packbf(float lo, float hi) {
  return (int)((unsigned)f2bf(lo) | ((unsigned)f2bf(hi) << 16));
}

__device__ __forceinline__ void gll16(const void* g, void* l) {
  __builtin_amdgcn_global_load_lds(
      (const __attribute__((address_space(1))) void*)g,
      (__attribute__((address_space(3))) void*)l, 16, 0, 0);
}

__device__ __forceinline__ f32x4 MFMA(short8 a, short8 b, f32x4 c) {
  return __builtin_amdgcn_mfma_f32_16x16x32_bf16(a, b, c, 0, 0, 0);
}
__device__ __forceinline__ f32x16 MFMA32(short8 a, short8 b, f32x16 c) {
  return __builtin_amdgcn_mfma_f32_32x32x16_bf16(a, b, c, 0, 0, 0);
}

// ---------------- prep kernels ----------------

__global__ void conv_bf16(const float* __restrict__ in, unsigned short* __restrict__ out, int n4) {
  for (int i = blockIdx.x * blockDim.x + threadIdx.x; i < n4; i += gridDim.x * blockDim.x) {
    float4 v = ((const float4*)in)[i];
    us4 o;
    o[0] = f2bf(v.x); o[1] = f2bf(v.y); o[2] = f2bf(v.z); o[3] = f2bf(v.w);
    ((us4*)out)[i] = o;
  }
}

// in: fp32 [R][C] -> out: bf16 [C][R], scaled
__global__ void tconv(const float* __restrict__ in, unsigned short* __restrict__ out,
                      int R, int C, float scale) {
  __shared__ float tile[32][33];
  int bx = blockIdx.x, by = blockIdx.y;
  int tx = threadIdx.x, ty = threadIdx.y;
#pragma unroll
  for (int i = 0; i < 4; ++i)
    tile[ty + i * 8][tx] = in[(long)(by * 32 + ty + i * 8) * C + bx * 32 + tx];
  __syncthreads();
#pragma unroll
  for (int i = 0; i < 4; ++i)
    out[(long)(bx * 32 + ty + i * 8) * R + by * 32 + tx] = f2bf(tile[tx][ty + i * 8] * scale);
}

// C[128][128] = A[128][64] @ B[64][128]   (fp32, tiny)
__global__ void fold_wc(const float* __restrict__ A, const float* __restrict__ Bm,
                        float* __restrict__ Cm) {
  int j = threadIdx.x;
  int m = blockIdx.x;
  float acc = 0.f;
#pragma unroll
  for (int l = 0; l < 64; ++l) acc += A[m * 64 + l] * Bm[l * 128 + j];
  Cm[m * 128 + j] = acc;
}

// We[k][h*128+j] = sum_m W[k][h*128+m] * Wc[m][j]
__global__ void make_eff(const float* __restrict__ W, const float* __restrict__ Wc,
                         float* __restrict__ We) {
  int j = threadIdx.x;
  int k = blockIdx.x;
  int h = blockIdx.y;
  const float* wrow = W + (long)k * 512 + h * 128;
  float acc = 0.f;
#pragma unroll 8
  for (int m = 0; m < 128; ++m) acc += wrow[m] * Wc[m * 128 + j];
  We[(long)k * 512 + h * 128 + j] = acc;
}

// ---------------- fused K+V projection GEMM (128^2 m97 structure, N=1024) ----------------
__global__ __launch_bounds__(256, 2) void gemm_kv(const unsigned short* __restrict__ A,
                                                  const unsigned short* __restrict__ BT,
                                                  unsigned short* __restrict__ Kout,
                                                  unsigned short* __restrict__ Vout) {
  const int K = 2048;
  __shared__ unsigned short As[128 * 32];
  __shared__ unsigned short Bs[128 * 32];
  const int tid = threadIdx.x;
  const int lane = tid & 63, w = tid >> 6;
  const int wr = w >> 1, wc = w & 1;
  const int c = lane & 15, hi = lane >> 4;
  const int nbn = 8;  // N=1024
  int bid = blockIdx.x;
  bid = (bid & 7) * (gridDim.x >> 3) + (bid >> 3);
  const int bm = bid / nbn, bn = bid % nbn;
  const int row0 = bm << 7, col0 = bn << 7;

  const unsigned short* ga = A + (long)(row0 + (tid >> 2)) * K + ((tid & 3) << 3);
  const unsigned short* gb = BT + (long)(col0 + (tid >> 2)) * K + ((tid & 3) << 3);
  unsigned short* la = As + tid * 8;
  unsigned short* lb = Bs + tid * 8;
  const long sA = (long)64 * K;

  f32x4 acc[4][4] = {};

  for (int k0 = 0; k0 < K; k0 += 32) {
    __syncthreads();
    gll16(ga + k0, la);
    gll16(ga + sA + k0, la + 2048);
    gll16(gb + k0, lb);
    gll16(gb + sA + k0, lb + 2048);
    __syncthreads();
    short8 a[4], b[4];
#pragma unroll
    for (int m = 0; m < 4; ++m)
      a[m] = *(const short8*)&As[(wr * 64 + m * 16 + c) * 32 + hi * 8];
#pragma unroll
    for (int n = 0; n < 4; ++n)
      b[n] = *(const short8*)&Bs[(wc * 64 + n * 16 + c) * 32 + hi * 8];
#pragma unroll
    for (int m = 0; m < 4; ++m)
#pragma unroll
      for (int n = 0; n < 4; ++n) acc[m][n] = MFMA(a[m], b[n], acc[m][n]);
  }

  if (col0 < 512) {  // K part: row-major bf16 [8192][512]
#pragma unroll
    for (int m = 0; m < 4; ++m) {
      int r0 = row0 + wr * 64 + m * 16 + hi * 4;
#pragma unroll
      for (int n = 0; n < 4; ++n) {
        int cc = col0 + wc * 64 + n * 16 + c;
#pragma unroll
        for (int j = 0; j < 4; ++j) Kout[(long)(r0 + j) * 512 + cc] = f2bf(acc[m][n][j]);
      }
    }
  } else {  // V part: transposed bf16 [512][8192]
#pragma unroll
    for (int m = 0; m < 4; ++m) {
      int r0 = row0 + wr * 64 + m * 16 + hi * 4;
#pragma unroll
      for (int n = 0; n < 4; ++n) {
        int cc = col0 - 512 + wc * 64 + n * 16 + c;
        us4 v;
#pragma unroll
        for (int j = 0; j < 4; ++j) v[j] = f2bf(acc[m][n][j]);
        *(us4*)&Vout[(long)cc * 8192 + r0] = v;
      }
    }
  }
}

// ---------------- GEMM 256x256, BK=32 ring-4 pipeline, counted vmcnt (T3+T4) ----------------
template <int EPI>
__global__ __launch_bounds__(512, 1) void gemm256(const unsigned short* __restrict__ A,
                                                  const unsigned short* __restrict__ BT,
                                                  void* __restrict__ Cout, int M, int N, int K) {
  __shared__ unsigned short S[4][2][8192];
  const int tid = threadIdx.x;
  const int lane = tid & 63, w = tid >> 6;
  const int wr = w >> 2, wc = w & 3;
  const int c = lane & 15, hi = lane >> 4;
  const int nbn = N >> 8;
  int bid = blockIdx.x;
  bid = (bid & 7) * (gridDim.x >> 3) + (bid >> 3);
  const int bm = bid / nbn, bn = bid % nbn;
  const int row0 = bm << 8, col0 = bn << 8;

  const unsigned short* ga0 = A + (long)(row0 + (tid >> 2)) * K + ((tid & 3) << 3);
  const unsigned short* ga1 = A + (long)(row0 + 128 + (tid >> 2)) * K + ((tid & 3) << 3);
  const unsigned short* gb0 = BT + (long)(col0 + (tid >> 2)) * K + ((tid & 3) << 3);
  const unsigned short* gb1 = BT + (long)(col0 + 128 + (tid >> 2)) * K + ((tid & 3) << 3);
  const int d0 = tid * 16;

#define STG(U)                                            \
  do {                                                    \
    const int s_ = (U) & 3;                               \
    const int ko_ = (U) * 32;                             \
    gll16(ga0 + ko_, (char*)S[s_][0] + d0);               \
    gll16(ga1 + ko_, (char*)S[s_][0] + 8192 + d0);        \
    gll16(gb0 + ko_, (char*)S[s_][1] + d0);               \
    gll16(gb1 + ko_, (char*)S[s_][1] + 8192 + d0);        \
  } while (0)

  f32x4 acc[8][4] = {};
  const int NC = K >> 5;

  STG(0);
  STG(1);
  STG(2);

  for (int u = 0; u < NC; ++u) {
    __builtin_amdgcn_s_barrier();
    if (u + 3 < NC) STG(u + 3);
    const int nafter = NC - 1 - u;
    if (nafter >= 3)
      asm volatile("s_waitcnt vmcnt(12)" ::: "memory");
    else if (nafter == 2)
      asm volatile("s_waitcnt vmcnt(8)" ::: "memory");
    else if (nafter == 1)
      asm volatile("s_waitcnt vmcnt(4)" ::: "memory");
    else
      asm volatile("s_waitcnt vmcnt(0)" ::: "memory");
    __builtin_amdgcn_s_barrier();
    __builtin_amdgcn_sched_barrier(0);

    const unsigned short* As = S[u & 3][0];
    const unsigned short* Bs = S[u & 3][1];
    short8 a[8], b[4];
#pragma unroll
    for (int mf = 0; mf < 8; ++mf)
      a[mf] = *(const short8*)&As[(wr * 128 + mf * 16 + c) * 32 + hi * 8];
#pragma unroll
    for (int nf = 0; nf < 4; ++nf)
      b[nf] = *(const short8*)&Bs[(wc * 64 + nf * 16 + c) * 32 + hi * 8];
    __builtin_amdgcn_s_setprio(1);
#pragma unroll
    for (int mf = 0; mf < 8; ++mf)
#pragma unroll
      for (int nf = 0; nf < 4; ++nf) acc[mf][nf] = MFMA(a[mf], b[nf], acc[mf][nf]);
    __builtin_amdgcn_s_setprio(0);
  }

  if (EPI == 0) {
    unsigned short* C = (unsigned short*)Cout;
#pragma unroll
    for (int mf = 0; mf < 8; ++mf) {
      int r0 = row0 + wr * 128 + mf * 16 + hi * 4;
#pragma unroll
      for (int nf = 0; nf < 4; ++nf) {
        int cc = col0 + wc * 64 + nf * 16 + c;
#pragma unroll
        for (int j = 0; j < 4; ++j) C[(long)(r0 + j) * N + cc] = f2bf(acc[mf][nf][j]);
      }
    }
  } else {
    float* C = (float*)Cout;
#pragma unroll
    for (int mf = 0; mf < 8; ++mf) {
      int r0 = row0 + wr * 128 + mf * 16 + hi * 4;
#pragma unroll
      for (int nf = 0; nf < 4; ++nf) {
        int cc = col0 + wc * 64 + nf * 16 + c;
#pragma unroll
        for (int j = 0; j < 4; ++j) C[(long)(r0 + j) * N + cc] = acc[mf][nf][j];
      }
    }
  }
#undef STG
}

// ---------------- attention: 8-warp 32x32 swapped-QK^T, 16-way LDS swizzles ----------------
// K tile: [64 keys][256B], byte ^= (key&15)<<4  -> conflict-free column-slice reads.
// V tile: 256B LDS rows hold d-pairs: row=d>>1, inner=(d&1)*128+key*2, byte ^= ((d>>1)&15)<<4.
__global__ __launch_bounds__(512, 1) void attn_kernel(const unsigned short* __restrict__ Q,
                                                      const unsigned short* __restrict__ Kr,
                                                      const unsigned short* __restrict__ VT,
                                                      unsigned short* __restrict__ CTX) {
  const int qt = blockIdx.x, h = blockIdx.y, b = blockIdx.z;
  const int kvh = h >> 2;
  const int tid = threadIdx.x, lane = tid & 63, w = tid >> 6;
  const int q31 = lane & 31, hi = lane >> 5;

  __shared__ unsigned short Ks[2][64 * 128];
  __shared__ unsigned short Vs[2][128 * 64];
  __shared__ float tab[8][32];

  const long qrow = (long)(b * 2048 + qt * 256 + w * 32 + q31);
  short8 qf[8];
#pragma unroll
  for (int st = 0; st < 8; ++st)
    qf[st] = *(const short8*)&Q[qrow * 2048 + h * 128 + st * 16 + hi * 8];

  f32x16 acc[4] = {};
  float mrow = -1e30f, lrow = 0.f;

  const unsigned short* kbase = Kr + (long)b * 2048 * 512 + kvh * 128;
  const unsigned short* vbase = VT + (long)kvh * 128 * 8192 + b * 2048;

  // staging geometry: linear LDS dest, inverse-swizzled global source
  int kp[2], vp[2];
  long kgo[2], vgo[2];
#pragma unroll
  for (int i = 0; i < 2; ++i) {
    int p = i * 8192 + tid * 16;
    // K: row = key (256B), 16-way XOR
    int key = p >> 8;
    kgo[i] = (long)key * 512 + (((p & 255) ^ ((key & 15) << 4)) >> 1);
    kp[i] = p;
    // V: 256B row = d-pair; invert swizzle to find (d, key) for this linear slot
    int r256 = p >> 8;
    int inrow = (p & 255) ^ ((r256 & 15) << 4);
    int d = r256 * 2 + (inrow >> 7);
    vgo[i] = (long)d * 8192 + ((inrow & 127) >> 1);
    vp[i] = p;
  }

#define STAGE(T, BUF)                                        \
  do {                                                       \
    const long ko_ = (long)(T) * 32768;                      \
    const int vo_ = (T) * 64;                                \
    gll16(kbase + ko_ + kgo[0], (char*)Ks[BUF] + kp[0]);     \
    gll16(kbase + ko_ + kgo[1], (char*)Ks[BUF] + kp[1]);     \
    gll16(vbase + vo_ + vgo[0], (char*)Vs[BUF] + vp[0]);     \
    gll16(vbase + vo_ + vgo[1], (char*)Vs[BUF] + vp[1]);     \
  } while (0)

  STAGE(0, 0);
  __syncthreads();

  const int kx = (q31 & 15) << 4;  // K-read XOR (same for row q31 and 32+q31)

  for (int t = 0; t < 32; ++t) {
    const int cur = t & 1;
    if (t < 31) STAGE(t + 1, cur ^ 1);

    const char* ks = (const char*)Ks[cur];
    const char* vs = (const char*)Vs[cur];

    // S = mfma(K, Q): s0 = keys 0-31, s1 = keys 32-63; lane col = own q
    f32x16 s0 = {}, s1 = {};
    __builtin_amdgcn_s_setprio(1);
#pragma unroll
    for (int st = 0; st < 8; ++st) {
      int col = (st * 32 + hi * 16) ^ kx;
      short8 k0 = *(const short8*)(ks + q31 * 256 + col);
      short8 k1 = *(const short8*)(ks + (32 + q31) * 256 + col);
      s0 = MFMA32(k0, qf[st], s0);
      s1 = MFMA32(k1, qf[st], s1);
    }
    __builtin_amdgcn_s_setprio(0);

    // row max: 31 in-register fmax + cross-half exchange
    float tl = s0[0];
#pragma unroll
    for (int e = 1; e < 16; ++e) tl = fmaxf(tl, s0[e]);
#pragma unroll
    for (int e = 0; e < 16; ++e) tl = fmaxf(tl, s1[e]);
    tl = fmaxf(tl, __shfl_xor(tl, 32));

    // defer-max rescale
    if (__any(tl > mrow + 11.0f)) {
      float mn = fmaxf(mrow, tl);
      float sc = __builtin_amdgcn_exp2f(mrow - mn);
      mrow = mn;
      lrow *= sc;
      if (lane < 32) tab[w][lane] = sc;
#pragma unroll
      for (int rg = 0; rg < 16; ++rg) {
        float scr = tab[w][(rg & 3) + 8 * (rg >> 2) + 4 * hi];
#pragma unroll
        for (int dblk = 0; dblk < 4; ++dblk) acc[dblk][rg] *= scr;
      }
    }

    // P = exp2(S - m); row sum
    float sum = 0.f;
#pragma unroll
    for (int e = 0; e < 16; ++e) {
      s0[e] = __builtin_amdgcn_exp2f(s0[e] - mrow);
      sum += s0[e];
    }
#pragma unroll
    for (int e = 0; e < 16; ++e) {
      s1[e] = __builtin_amdgcn_exp2f(s1[e] - mrow);
      sum += s1[e];
    }
    sum += __shfl_xor(sum, 32);
    lrow += sum;

    // pack P -> PV A-frags: RNE packs + offer-select exchange (2 shfl per kq)
    short8 ap[4];
#pragma unroll
    for (int kq = 0; kq < 4; ++kq) {
      int a0, a1, a2, a3;
      if (kq == 0) {
        a0 = packbf(s0[0], s0[1]);   a1 = packbf(s0[2], s0[3]);
        a2 = packbf(s0[4], s0[5]);   a3 = packbf(s0[6], s0[7]);
      } else if (kq == 1) {
        a0 = packbf(s0[8], s0[9]);   a1 = packbf(s0[10], s0[11]);
        a2 = packbf(s0[12], s0[13]); a3 = packbf(s0[14], s0[15]);
      } else if (kq == 2) {
        a0 = packbf(s1[0], s1[1]);   a1 = packbf(s1[2], s1[3]);
        a2 = packbf(s1[4], s1[5]);   a3 = packbf(s1[6], s1[7]);
      } else {
        a0 = packbf(s1[8], s1[9]);   a1 = packbf(s1[10], s1[11]);
        a2 = packbf(s1[12], s1[13]); a3 = packbf(s1[14], s1[15]);
      }
      int off0 = hi ? a0 : a2;
      int off1 = hi ? a1 : a3;
      int r0 = __shfl_xor(off0, 32);
      int r1 = __shfl_xor(off1, 32);
      i32x4 tt;
      tt[0] = hi ? r0 : a0;
      tt[1] = hi ? r1 : a1;
      tt[2] = hi ? a2 : r0;
      tt[3] = hi ? a3 : r1;
      ap[kq] = __builtin_bit_cast(short8, tt);
    }

    // ctx += P V  (V read: d-pair rows, 16-way XOR)
    __builtin_amdgcn_s_setprio(1);
#pragma unroll
    for (int dblk = 0; dblk < 4; ++dblk) {
      int d = dblk * 32 + q31;
      int vbase_b = (d >> 1) * 256;
      int vx = ((d >> 1) & 15) << 4;
      int inr0 = (d & 1) * 128 + hi * 16;
#pragma unroll
      for (int kq = 0; kq < 4; ++kq) {
        short8 vv = *(const short8*)(vs + vbase_b + ((inr0 + kq * 32) ^ vx));
        acc[dblk] = MFMA32(ap[kq], vv, acc[dblk]);
      }
    }
    __builtin_amdgcn_s_setprio(0);

    __syncthreads();
  }

  if (lane < 32) tab[w][lane] = 1.0f / lrow;
#pragma unroll
  for (int rg = 0; rg < 16; ++rg) {
    int qr = (rg & 3) + 8 * (rg >> 2) + 4 * hi;
    float il = tab[w][qr];
    long grow = (long)(b * 2048 + qt * 256 + w * 32 + qr);
#pragma unroll
    for (int dblk = 0; dblk < 4; ++dblk)
      CTX[grow * 2048 + h * 128 + dblk * 32 + q31] = f2bf(acc[dblk][rg] * il);
  }
#undef STAGE
}

// ---------------- launch ----------------

extern "C" void kernel_launch(void* const* d_in, const int* in_sizes, int n_in, void* d_out,
                              int out_size, void* d_ws, size_t ws_size, hipStream_t stream) {
  (void)in_sizes; (void)n_in; (void)out_size; (void)ws_size;
  const float* x    = (const float*)d_in[0];
  const float* W_q  = (const float*)d_in[1];
  const float* W_k  = (const float*)d_in[2];
  const float* W_v  = (const float*)d_in[3];
  const float* Wk2l = (const float*)d_in[4];
  const float* Wv2l = (const float*)d_in[5];
  const float* Wkfl = (const float*)d_in[6];
  const float* Wvfl = (const float*)d_in[7];
  const float* W_o  = (const float*)d_in[8];
  float* out = (float*)d_out;

  char* ws = (char*)d_ws;
  unsigned short* Xb   = (unsigned short*)(ws + 0);          // 32 MiB (reused as CTXb)
  unsigned short* Qb   = (unsigned short*)(ws + 33554432);   // 32 MiB
  unsigned short* KRb  = (unsigned short*)(ws + 67108864);   // 8 MiB
  unsigned short* VTb  = (unsigned short*)(ws + 75497472);   // 8 MiB
  unsigned short* WqT  = (unsigned short*)(ws + 83886080);   // 8 MiB
  unsigned short* WoT  = (unsigned short*)(ws + 92274688);   // 8 MiB
  unsigned short* WkeT = (unsigned short*)(ws + 100663296);  // 2 MiB  (rows 0-511 of fused B^T)
  unsigned short* WveT = (unsigned short*)(ws + 102760448);  // 2 MiB  (rows 512-1023, contiguous)
  float* Wkc    = (float*)(ws + 104857600);                  // 64 KiB
  float* Wvc    = (float*)(ws + 104923136);                  // 64 KiB
  float* Wstage = (float*)(ws + 104988672);                  // 4 MiB
  unsigned short* CTXb = Xb;

  // dtype conversion + weight folding (W_q scale includes 1/sqrt(Dh) AND log2e)
  conv_bf16<<<2048, 256, 0, stream>>>(x, Xb, 16777216 / 4);
  tconv<<<dim3(64, 64), dim3(32, 8), 0, stream>>>(W_q, WqT, 2048, 2048,
                                                  (float)(0.088388347648318447 * 1.4426950408889634));
  tconv<<<dim3(64, 64), dim3(32, 8), 0, stream>>>(W_o, WoT, 2048, 2048, 1.0f);
  fold_wc<<<128, 128, 0, stream>>>(Wk2l, Wkfl, Wkc);
  fold_wc<<<128, 128, 0, stream>>>(Wv2l, Wvfl, Wvc);
  make_eff<<<dim3(2048, 4), 128, 0, stream>>>(W_k, Wkc, Wstage);
  tconv<<<dim3(16, 64), dim3(32, 8), 0, stream>>>(Wstage, WkeT, 2048, 512, 1.0f);
  make_eff<<<dim3(2048, 4), 128, 0, stream>>>(W_v, Wvc, Wstage);
  tconv<<<dim3(16, 64), dim3(32, 8), 0, stream>>>(Wstage, WveT, 2048, 512, 1.0f);

  // projections: Q on 256^2 pipeline; K+V fused (N=1024, 512 blocks, full GPU)
  gemm256<0><<<256, 512, 0, stream>>>(Xb, WqT, Qb, 8192, 2048, 2048);
  gemm_kv<<<512, 256, 0, stream>>>(Xb, WkeT, KRb, VTb);

  // attention (8-warp 32x32 structure, conflict-free LDS)
  attn_kernel<<<dim3(8, 16, 4), 512, 0, stream>>>(Qb, KRb, VTb, CTXb);

  // output projection -> fp32 d_out
  gemm256<2><<<256, 512, 0, stream>>>(CTXb, WoT, out, 8192, 2048, 2048);
}